// Round 3
// baseline (208.824 us; speedup 1.0000x reference)
//
#include <hip/hip_runtime.h>

#define HW 256
#define HWMASK 255
#define CH 128
#define BATCH 8
#define NK 4
#define TSX 128
#define TSY 64
#define LDQ 35   // float4 quads per LDS row stride (560B, odd -> bank spread)
#define NQ 34    // data quads per row (136 floats: cols x0-4 .. x0+131)

__device__ __forceinline__ int srow(int r) { return ((r >> 2) + r) & 7; }
__device__ __forceinline__ int wswz(int q, int s) { return q < 32 ? (q ^ s) : q; }

// ---------------- Kernel A1: partial sums of guidance ----------------
__global__ __launch_bounds__(256) void mean1_kernel(const float* __restrict__ guid,
                                                    float* __restrict__ partial) {
    int blk = blockIdx.x;
    const float4* p = (const float4*)(guid + (size_t)blk * 16384);
    float s = 0.f;
    for (int i = threadIdx.x; i < 4096; i += 256) {
        float4 v = p[i];
        s += (v.x + v.y) + (v.z + v.w);
    }
    for (int off = 32; off; off >>= 1) s += __shfl_down(s, off, 64);
    __shared__ float red[4];
    if ((threadIdx.x & 63) == 0) red[threadIdx.x >> 6] = s;
    __syncthreads();
    if (threadIdx.x == 0) partial[blk] = (red[0] + red[1]) + (red[2] + red[3]);
}

// ---------------- Kernel B: finalize means + MLP + softmax ----------------
__global__ __launch_bounds__(256) void mlp_kernel(const float* __restrict__ partial,
                                                  const float* __restrict__ w1,
                                                  const float* __restrict__ b1,
                                                  const float* __restrict__ w2,
                                                  const float* __restrict__ b2,
                                                  float* __restrict__ wt) {
    __shared__ float gs[BATCH * CH];
    __shared__ float h1[BATCH * 32];
    __shared__ float lg[BATCH * NK];
    int t = threadIdx.x;
    for (int i = t; i < BATCH * CH; i += 256) {
        float4 v = *(const float4*)(partial + i * 4);
        gs[i] = ((v.x + v.y) + (v.z + v.w)) * (1.0f / 65536.0f);
    }
    __syncthreads();
    {
        int b = t >> 5, j = t & 31;
        float acc = b1[j];
        #pragma unroll 4
        for (int c = 0; c < CH; ++c) acc += gs[b * CH + c] * w1[j * CH + c];
        h1[b * 32 + j] = fmaxf(acc, 0.f);
    }
    __syncthreads();
    if (t < BATCH * NK) {
        int b = t >> 2, k = t & 3;
        float acc = b2[k];
        #pragma unroll
        for (int j = 0; j < 32; ++j) acc += h1[b * 32 + j] * w2[k * 32 + j];
        lg[b * NK + k] = acc;
    }
    __syncthreads();
    if (t < BATCH) {
        int b = t;
        float m = lg[b * 4];
        for (int k = 1; k < 4; ++k) m = fmaxf(m, lg[b * 4 + k]);
        float e[4], s = 0.f;
        for (int k = 0; k < 4; ++k) { e[k] = expf(lg[b * 4 + k] - m); s += e[k]; }
        float inv = 1.0f / s;
        for (int k = 0; k < 4; ++k) wt[b * 4 + k] = e[k] * inv;
    }
}

// ---------------- Kernel C: dyn = blend of basis filters, stored FLIPPED ----------------
__global__ __launch_bounds__(256) void dyn_kernel(const float* __restrict__ wt,
                                                  const float* __restrict__ basis,
                                                  float* __restrict__ dynF) {
    int idx = blockIdx.x * 256 + threadIdx.x;
    if (idx >= BATCH * CH * 49) return;
    int ij = idx % 49;
    int bc = idx / 49;
    int c = bc % CH;
    int b = bc / CH;
    float acc = 0.f;
    #pragma unroll
    for (int k = 0; k < NK; ++k)
        acc += wt[b * NK + k] * basis[(k * CH + c) * 49 + ij];
    dynF[bc * 49 + (48 - ij)] = acc;
}

// ---------------- Kernel D: circular depthwise 7x7 conv, 128x64 tile ----------------
__global__ __launch_bounds__(256) void conv_kernel(const float* __restrict__ x,
                                                   const float* __restrict__ dynF,
                                                   float* __restrict__ out) {
    int bc = blockIdx.z;
    int x0 = blockIdx.x * TSX;
    int y0 = blockIdx.y * TSY;
    __shared__ float4 lds4[70 * LDQ];
    const float* xp = x + (size_t)bc * (HW * HW);

    // filter taps: block-uniform address -> scalar loads into SGPRs
    const float* df = dynF + bc * 49;
    float d[49];
    #pragma unroll
    for (int i = 0; i < 49; ++i) d[i] = df[i];

    // stage 70 rows x 34 quads (LDS origin = global col x0-4)
    int tid = threadIdx.x;
    {
        int e = tid;
        int r = e / NQ;
        int c = e - r * NQ;
        #pragma unroll
        for (int it = 0; it < 10; ++it) {
            if (e < 70 * NQ) {
                int gy = (y0 + r - 3) & HWMASK;
                int gx = (x0 + 4 * c - 4) & HWMASK;
                float4 v = *(const float4*)(xp + gy * HW + gx);
                lds4[r * LDQ + wswz(c, srow(r))] = v;
            }
            e += 256; c += 18; r += 7;
            if (c >= NQ) { c -= NQ; r += 1; }
        }
    }
    __syncthreads();

    int tx = tid & 15, ty = tid >> 4;   // wave: tx 0..15, ty 0..3
    int lx0 = 8 * tx, ly0 = 4 * ty;
    float acc[4][8] = {};
    #pragma unroll
    for (int rr = 0; rr < 10; ++rr) {
        int r = ly0 + rr;
        int s = srow(r);
        int rb = r * LDQ;
        float4 A = lds4[rb + wswz(2 * tx,     s)];
        float4 B = lds4[rb + wswz(2 * tx + 1, s)];
        float4 C = lds4[rb + wswz(2 * tx + 2, s)];
        float4 D = lds4[rb + wswz(2 * tx + 3, s)];
        float v[16] = {A.x, A.y, A.z, A.w, B.x, B.y, B.z, B.w,
                       C.x, C.y, C.z, C.w, D.x, D.y, D.z, D.w};
        #pragma unroll
        for (int rq = 0; rq < 4; ++rq) {
            int ii = rr - rq;
            if (ii >= 0 && ii <= 6) {
                #pragma unroll
                for (int q = 0; q < 8; ++q) {
                    #pragma unroll
                    for (int jj = 0; jj < 7; ++jj)
                        acc[rq][q] += d[ii * 7 + jj] * v[q + jj + 1];
                }
            }
        }
    }
    float* op = out + (size_t)bc * (HW * HW) + x0 + lx0;
    #pragma unroll
    for (int rq = 0; rq < 4; ++rq) {
        float4 o0 = {acc[rq][0], acc[rq][1], acc[rq][2], acc[rq][3]};
        float4 o1 = {acc[rq][4], acc[rq][5], acc[rq][6], acc[rq][7]};
        float* row = op + (y0 + ly0 + rq) * HW;
        *(float4*)(row)     = o0;
        *(float4*)(row + 4) = o1;
    }
}

extern "C" void kernel_launch(void* const* d_in, const int* in_sizes, int n_in,
                              void* d_out, int out_size, void* d_ws, size_t ws_size,
                              hipStream_t stream) {
    const float* x        = (const float*)d_in[0];
    const float* guidance = (const float*)d_in[1];
    const float* basis    = (const float*)d_in[2];
    const float* w1       = (const float*)d_in[3];
    const float* b1       = (const float*)d_in[4];
    const float* w2       = (const float*)d_in[5];
    const float* b2       = (const float*)d_in[6];
    float* out = (float*)d_out;
    float* ws  = (float*)d_ws;

    float* partial = ws;                  // 4096
    float* wt      = ws + 4096;           // 32
    float* dynF    = ws + 4096 + 32;      // 50176

    mean1_kernel<<<4096, 256, 0, stream>>>(guidance, partial);
    mlp_kernel<<<1, 256, 0, stream>>>(partial, w1, b1, w2, b2, wt);
    dyn_kernel<<<(BATCH * CH * 49 + 255) / 256, 256, 0, stream>>>(wt, basis, dynF);
    conv_kernel<<<dim3(HW / TSX, HW / TSY, BATCH * CH), 256, 0, stream>>>(x, dynF, out);
}